// Round 5
// baseline (886.329 us; speedup 1.0000x reference)
//
#include <hip/hip_runtime.h>

#define B_ 16
#define N_ 1024
#define F_ 768
#define H_ 128

typedef float f32x4 __attribute__((ext_vector_type(4)));
typedef short s16x8 __attribute__((ext_vector_type(8)));
typedef unsigned short u16;
typedef u16 u16x8 __attribute__((ext_vector_type(8)));
typedef u16 u16x4 __attribute__((ext_vector_type(4)));

static const long NN_ = (long)N_ * N_;

__device__ __forceinline__ u16 f2b(float f) {
  unsigned u = __float_as_uint(f);
  unsigned r = (u + 0x7FFFu + ((u >> 16) & 1u)) >> 16;
  return (u16)r;
}
__device__ __forceinline__ float b2f(u16 u) {
  return __uint_as_float(((unsigned)u) << 16);
}

// ---------------------------------------------------------------------------
__device__ __forceinline__ float blockReduceSum256(float v) {
  __shared__ float red[4];
  #pragma unroll
  for (int o = 32; o > 0; o >>= 1) v += __shfl_down(v, o, 64);
  if ((threadIdx.x & 63) == 0) red[threadIdx.x >> 6] = v;
  __syncthreads();
  float r = red[0] + red[1] + red[2] + red[3];
  __syncthreads();
  return r;
}

// ---------------------------------------------------------------------------
// K1: dis_bin = rsqrt(1+nnz), dc = rsqrt(1+rowsum), dr = mask*dc
// ---------------------------------------------------------------------------
__global__ __launch_bounds__(256) void k_degrees(
    const float* __restrict__ adj, float* __restrict__ dis_bin,
    float* __restrict__ dr, float* __restrict__ dc) {
  long row = blockIdx.x;
  const float* a = adj + row * N_;
  float cnt = 0.f, sw = 0.f;
  for (int j = threadIdx.x; j < N_; j += 256) {
    float v = a[j];
    if (v != 0.0f) { cnt += 1.0f; sw += v; }
  }
  __shared__ float r1[4], r2[4];
  #pragma unroll
  for (int o = 32; o > 0; o >>= 1) { cnt += __shfl_down(cnt, o, 64); sw += __shfl_down(sw, o, 64); }
  if ((threadIdx.x & 63) == 0) { r1[threadIdx.x >> 6] = cnt; r2[threadIdx.x >> 6] = sw; }
  __syncthreads();
  if (threadIdx.x == 0) {
    float c = r1[0] + r1[1] + r1[2] + r1[3];
    float s = r2[0] + r2[1] + r2[2] + r2[3];
    dis_bin[row] = rsqrtf(c + 1.0f);
    float d = rsqrtf(s + 1.0f);
    dc[row] = d;
    dr[row] = (s > 0.0f) ? d : 0.0f;
  }
}

// ---------------------------------------------------------------------------
// split f32 -> 3 bf16 planes (h+m+l captures ~24 mantissa bits)
// ---------------------------------------------------------------------------
__global__ __launch_bounds__(256) void k_split3(
    const float* __restrict__ X, u16* __restrict__ Yh, u16* __restrict__ Ym,
    u16* __restrict__ Yl, long n4) {
  long i = (long)blockIdx.x * 256 + threadIdx.x;
  long stride = (long)gridDim.x * 256;
  for (; i < n4; i += stride) {
    f32x4 v = *(const f32x4*)(X + i * 4);
    u16x4 oh, om, ol;
    #pragma unroll
    for (int e = 0; e < 4; ++e) {
      float f = v[e];
      u16 h = f2b(f); float r1 = f - b2f(h);
      u16 m = f2b(r1); float r2 = r1 - b2f(m);
      u16 l = f2b(r2);
      oh[e] = h; om[e] = m; ol[e] = l;
    }
    *(u16x4*)(Yh + i * 4) = oh;
    *(u16x4*)(Ym + i * 4) = om;
    *(u16x4*)(Yl + i * 4) = ol;
  }
}

// transpose W1 [F][H] -> [H][F] with 3-way split
__global__ __launch_bounds__(256) void k_convT3(
    const float* __restrict__ X, u16* __restrict__ Yh, u16* __restrict__ Ym,
    u16* __restrict__ Yl) {
  __shared__ float tile[32][33];
  int tx = threadIdx.x & 31, ty = threadIdx.x >> 5;
  int r0 = blockIdx.y * 32, c0 = blockIdx.x * 32;  // r: F dim, c: H dim
  #pragma unroll
  for (int i = 0; i < 4; ++i)
    tile[ty + i * 8][tx] = X[(long)(r0 + ty + i * 8) * H_ + (c0 + tx)];
  __syncthreads();
  #pragma unroll
  for (int i = 0; i < 4; ++i) {
    float v = tile[tx][ty + i * 8];
    long o = (long)(c0 + ty + i * 8) * F_ + (r0 + tx);
    u16 h = f2b(v); float r1 = v - b2f(h);
    u16 m = f2b(r1); float r2 = r1 - b2f(m);
    u16 l = f2b(r2);
    Yh[o] = h; Ym[o] = m; Yl[o] = l;
  }
}

// ---------------------------------------------------------------------------
// G1: P1 = scale .* ((A0+A1+A2) @ (B0+B1+B2)^T), 6-product split-3 MFMA.
// A planes [M][K] bf16, B planes [N][K] bf16. 64x64 tile.
// ---------------------------------------------------------------------------
__global__ __launch_bounds__(256) void mgemm64s3(
    const u16* __restrict__ A0, const u16* __restrict__ A1, const u16* __restrict__ A2,
    const u16* __restrict__ B0, const u16* __restrict__ B1, const u16* __restrict__ B2,
    float* __restrict__ C, int N, int K, const float* __restrict__ scale) {
  int m0 = blockIdx.y * 64, n0 = blockIdx.x * 64;
  __shared__ __align__(16) u16 As[3][64 * 72];
  __shared__ __align__(16) u16 Bs[3][64 * 72];
  const u16* Ap[3] = {A0 + (long)m0 * K, A1 + (long)m0 * K, A2 + (long)m0 * K};
  const u16* Bp[3] = {B0 + (long)n0 * K, B1 + (long)n0 * K, B2 + (long)n0 * K};
  int tid = threadIdx.x, lane = tid & 63, wave = tid >> 6;
  int wr = wave >> 1, wc = wave & 1, kg = lane >> 4, r16 = lane & 15;
  f32x4 acc[2][2] = {};

  for (int k0 = 0; k0 < K; k0 += 64) {
    #pragma unroll
    for (int t = 0; t < 3; ++t) {
      #pragma unroll
      for (int i = 0; i < 2; ++i) {
        int u = tid + i * 256;
        int row = u >> 3, seg = u & 7;
        *(u16x8*)(&As[t][row * 72 + seg * 8]) = *(const u16x8*)(Ap[t] + (long)row * K + k0 + seg * 8);
        *(u16x8*)(&Bs[t][row * 72 + seg * 8]) = *(const u16x8*)(Bp[t] + (long)row * K + k0 + seg * 8);
      }
    }
    __syncthreads();
    #pragma unroll
    for (int kk = 0; kk < 2; ++kk) {
      s16x8 ah[2], am[2], al[2], bh[2], bm[2], bl[2];
      #pragma unroll
      for (int m = 0; m < 2; ++m) {
        int off = (wr * 32 + m * 16 + r16) * 72 + kk * 32 + kg * 8;
        ah[m] = *(const s16x8*)(&As[0][off]);
        am[m] = *(const s16x8*)(&As[1][off]);
        al[m] = *(const s16x8*)(&As[2][off]);
      }
      #pragma unroll
      for (int n = 0; n < 2; ++n) {
        int off = (wc * 32 + n * 16 + r16) * 72 + kk * 32 + kg * 8;
        bh[n] = *(const s16x8*)(&Bs[0][off]);
        bm[n] = *(const s16x8*)(&Bs[1][off]);
        bl[n] = *(const s16x8*)(&Bs[2][off]);
      }
      #pragma unroll
      for (int m = 0; m < 2; ++m)
        #pragma unroll
        for (int n = 0; n < 2; ++n) {
          acc[m][n] = __builtin_amdgcn_mfma_f32_16x16x32_bf16(ah[m], bh[n], acc[m][n], 0, 0, 0);
          acc[m][n] = __builtin_amdgcn_mfma_f32_16x16x32_bf16(ah[m], bm[n], acc[m][n], 0, 0, 0);
          acc[m][n] = __builtin_amdgcn_mfma_f32_16x16x32_bf16(am[m], bh[n], acc[m][n], 0, 0, 0);
          acc[m][n] = __builtin_amdgcn_mfma_f32_16x16x32_bf16(am[m], bm[n], acc[m][n], 0, 0, 0);
          acc[m][n] = __builtin_amdgcn_mfma_f32_16x16x32_bf16(ah[m], bl[n], acc[m][n], 0, 0, 0);
          acc[m][n] = __builtin_amdgcn_mfma_f32_16x16x32_bf16(al[m], bh[n], acc[m][n], 0, 0, 0);
        }
    }
    __syncthreads();
  }

  #pragma unroll
  for (int m = 0; m < 2; ++m)
    #pragma unroll
    for (int r = 0; r < 4; ++r) {
      int row = m0 + wr * 32 + m * 16 + kg * 4 + r;
      float sc = scale[row];
      #pragma unroll
      for (int n = 0; n < 2; ++n) {
        int col = n0 + wc * 32 + n * 16 + r16;
        C[(long)row * N + col] = sc * acc[m][n][r];
      }
    }
}

// ---------------------------------------------------------------------------
// K2 (sparse, f32-exact): x1 = relu(dis_i*(sum_{adj_ij!=0} P1_j + P1_i) + b1)
// ---------------------------------------------------------------------------
__global__ __launch_bounds__(256) void k_spmm_relu(
    const float* __restrict__ adj, const float* __restrict__ P1,
    const float* __restrict__ dis_bin, const float* __restrict__ b1,
    float* __restrict__ x1) {
  long row = blockIdx.x;
  int b = (int)(row >> 10), i = (int)(row & 1023);
  const float* a = adj + row * N_;
  const float* Pb = P1 + (long)b * (long)N_ * H_;
  __shared__ int idxs[N_];
  __shared__ int tcnt[256];
  __shared__ float accs[H_];
  int tid = threadIdx.x;
  int base = tid * 4;
  f32x4 av = *(const f32x4*)(a + base);
  int c0 = (av[0] != 0.0f) + (av[1] != 0.0f) + (av[2] != 0.0f) + (av[3] != 0.0f);
  tcnt[tid] = c0;
  __syncthreads();
  for (int off = 1; off < 256; off <<= 1) {
    int add = (tid >= off) ? tcnt[tid - off] : 0;
    __syncthreads();
    tcnt[tid] += add;
    __syncthreads();
  }
  int pos = tcnt[tid] - c0;
  int n = tcnt[255];
  if (av[0] != 0.0f) idxs[pos++] = base;
  if (av[1] != 0.0f) idxs[pos++] = base + 1;
  if (av[2] != 0.0f) idxs[pos++] = base + 2;
  if (av[3] != 0.0f) idxs[pos++] = base + 3;
  __syncthreads();
  int c = tid & 127, team = tid >> 7;
  float acc = 0.f;
  for (int u = team; u < n; u += 2)
    acc += Pb[(long)idxs[u] * H_ + c];
  if (team == 1) accs[c] = acc;
  __syncthreads();
  if (team == 0) {
    float tot = acc + accs[c] + Pb[(long)i * H_ + c];
    float v = dis_bin[row] * tot + b1[c];
    x1[row * H_ + c] = fmaxf(v, 0.0f);
  }
}

// ---------------------------------------------------------------------------
// K4: t[row] = dot(x1[row,:], Watt)
// ---------------------------------------------------------------------------
__global__ __launch_bounds__(256) void k_att_dot(
    const float* __restrict__ x1, const float* __restrict__ Watt,
    float* __restrict__ t) {
  long row = blockIdx.x;
  float v = 0.f;
  if (threadIdx.x < H_) v = x1[row * H_ + threadIdx.x] * Watt[threadIdx.x];
  float s = blockReduceSum256(v);
  if (threadIdx.x == 0) t[row] = s;
}

// ---------------------------------------------------------------------------
// K5: alpha
// ---------------------------------------------------------------------------
__global__ __launch_bounds__(256) void k_alpha(
    const float* __restrict__ adj, const float* __restrict__ dis_bin,
    const float* __restrict__ t, const float* __restrict__ batt,
    float* __restrict__ alpha) {
  long row = blockIdx.x;
  int b = (int)(row >> 10), i = (int)(row & 1023);
  const float* a = adj + row * N_;
  const float* db = dis_bin + (long)b * N_;
  const float* tb = t + (long)b * N_;
  float s = 0.f;
  for (int j = threadIdx.x; j < N_; j += 256)
    if (a[j] != 0.0f) s += db[j] * tb[j];
  s = blockReduceSum256(s);
  if (threadIdx.x == 0) {
    float di = db[i];
    float pre = di * (s + di * tb[i]) + batt[0];
    float z = pre * pre;
    alpha[row] = 1.0f / (1.0f + expf(-z));
  }
}

// ---------------------------------------------------------------------------
// K6: per-batch stable descending sort, cut, index_mask, cut_alpha
// ---------------------------------------------------------------------------
__global__ __launch_bounds__(1024) void k_cutmask(
    const float* __restrict__ alpha, const int* __restrict__ num_sent,
    const int* __restrict__ nout, float* __restrict__ index_mask,
    float* __restrict__ ca) {
  int b = blockIdx.x, tid = threadIdx.x;
  __shared__ unsigned long long keys[N_];
  __shared__ int cs[N_];
  __shared__ int pos_s;
  float av = alpha[(long)b * N_ + tid];
  unsigned int bits = __float_as_uint(av);
  keys[tid] = ((unsigned long long)(0xFFFFFFFFu - bits) << 32) | (unsigned int)tid;
  __syncthreads();
  for (int kk = 2; kk <= N_; kk <<= 1) {
    for (int j = kk >> 1; j > 0; j >>= 1) {
      int ixj = tid ^ j;
      if (ixj > tid) {
        unsigned long long x = keys[tid], y = keys[ixj];
        bool up = ((tid & kk) == 0);
        if ((x > y) == up) { keys[tid] = y; keys[ixj] = x; }
      }
      __syncthreads();
    }
  }
  int ns = num_sent[b];
  int idx = (int)(keys[tid] & 0xFFFFFFFFull);
  cs[tid] = (idx < ns) ? 1 : 0;
  __syncthreads();
  for (int off = 1; off < N_; off <<= 1) {
    int add = (tid >= off) ? cs[tid - off] : 0;
    __syncthreads();
    cs[tid] += add;
    __syncthreads();
  }
  int k = nout[0];
  if (tid == 0) pos_s = 0;
  __syncthreads();
  if (cs[tid] >= k && (tid == 0 || cs[tid - 1] < k)) pos_s = tid;
  __syncthreads();
  float cut = __uint_as_float(0xFFFFFFFFu - (unsigned int)(keys[pos_s] >> 32));
  float myalpha = __uint_as_float(0xFFFFFFFFu - (unsigned int)(keys[tid] >> 32));
  index_mask[(long)b * N_ + idx] = (tid <= pos_s) ? 1.0f : 0.0f;
  ca[(long)b * N_ + idx] = fmaxf((myalpha + 1e-7f) - cut, 0.0f);
}

// ---------------------------------------------------------------------------
// K6b: sel/rank/nc = compaction of {j : ca[j] > 0}
// ---------------------------------------------------------------------------
__global__ __launch_bounds__(1024) void k_select(
    const float* __restrict__ ca, int* __restrict__ sel, int* __restrict__ rank,
    int* __restrict__ ncArr) {
  int b = blockIdx.x, tid = threadIdx.x;
  __shared__ int ps[N_];
  int flag = (ca[(long)b * N_ + tid] > 0.0f) ? 1 : 0;
  ps[tid] = flag;
  __syncthreads();
  for (int off = 1; off < N_; off <<= 1) {
    int add = (tid >= off) ? ps[tid - off] : 0;
    __syncthreads();
    ps[tid] += add;
    __syncthreads();
  }
  sel[(long)b * N_ + tid] = 0;
  rank[(long)b * N_ + tid] = -1;
  __syncthreads();
  if (flag) {
    sel[(long)b * N_ + ps[tid] - 1] = tid;
    rank[(long)b * N_ + tid] = ps[tid] - 1;
  }
  if (tid == N_ - 1) ncArr[b] = ps[N_ - 1];
}

// ---------------------------------------------------------------------------
// K7: S build + L1 row-normalize (dense out) + compact Sc bf16 emission
// ---------------------------------------------------------------------------
__global__ __launch_bounds__(256) void k_build_S(
    const float* __restrict__ adj, const float* __restrict__ dr,
    const float* __restrict__ dc, const float* __restrict__ ca,
    const int* __restrict__ rank, float* __restrict__ S,
    u16* __restrict__ Sc) {
  long row = blockIdx.x;
  int b = (int)(row >> 10), i = (int)(row & 1023);
  const float* a = adj + row * N_;
  const float* dcb = dc + (long)b * N_;
  const float* cab = ca + (long)b * N_;
  float dri = dr[row];
  __shared__ float pre[N_];
  __shared__ int ranks[N_];
  for (int j = threadIdx.x; j < N_; j += 256)
    ranks[j] = rank[(long)b * N_ + j];
  float ls = 0.f;
  for (int j = threadIdx.x; j < N_; j += 256) {
    float avv = a[j] + ((j == i) ? 1.0f : 0.0f);
    float v = dri * avv * dcb[j] * cab[j];
    pre[j] = v;
    ls += v;
  }
  float sum = blockReduceSum256(ls);
  float denom = fmaxf(sum, 1e-12f);
  for (int j = threadIdx.x; j < N_; j += 256) {
    float v = pre[j] / denom;
    S[row * N_ + j] = v;
    int rk = ranks[j];
    if (rk >= 0) Sc[(long)b * NN_ + (long)rk * N_ + i] = f2b(v);
  }
}

// ---------------------------------------------------------------------------
// Compact GEMM (f32 accum, early-exit on nc). 64x64 tile.
// A: [.][K] (bf16, or f32 if AF32), row optionally indirected via sel (SELA).
// B: BT=0 dense f32 [K][N] ; BT=1 bf16 [N'][K] (A·B^T).
// MODE 0: bf16 C[row][N] (row<nc) | 1: scatter floorq -> cadj[sel[r]][sel[c]]
// MODE 2: f32 scatter rows -> C[sel[r]][col] | 3: f32 C[row][col]=dis2c[row]*acc
// ---------------------------------------------------------------------------
#define TK 16

template<int AF32, int SELA, int BT, int MODE>
__global__ __launch_bounds__(256) void cgemm(
    const void* __restrict__ Av, const void* __restrict__ Bv, void* __restrict__ Cv,
    int N, int K, long sA, long sB, long sC,
    const int* __restrict__ ncArr, const int* __restrict__ sel,
    const float* __restrict__ dis2c) {
  int bz = blockIdx.z;
  int nc = ncArr[bz];
  int m0 = blockIdx.y * 64, n0 = blockIdx.x * 64;
  if (m0 >= nc) return;
  if (MODE == 1 && n0 >= nc) return;
  const int* selb = sel + (long)bz * N_;
  __shared__ float As[TK][65];
  __shared__ float Bs[TK][65];
  float acc[4][4] = {};
  int tid = threadIdx.x, tx = tid & 15, ty = tid >> 4;

  for (int k0 = 0; k0 < K; k0 += TK) {
    #pragma unroll
    for (int l = 0; l < 4; ++l) {
      int idx = tid + l * 256;
      int k = idx & 15, m = idx >> 4;
      int r = m0 + m;
      int ar = SELA ? selb[r] : r;
      float a;
      if (AF32) a = ((const float*)Av)[(long)bz * sA + (long)ar * K + k0 + k];
      else      a = b2f(((const u16*)Av)[(long)bz * sA + (long)ar * K + k0 + k]);
      As[k][m] = a;
    }
    #pragma unroll
    for (int l = 0; l < 4; ++l) {
      int idx = tid + l * 256;
      if (BT == 0) {
        int n = idx & 63, k = idx >> 6;
        Bs[k][n] = ((const float*)Bv)[(long)bz * sB + (long)(k0 + k) * N + (n0 + n)];
      } else {
        int k = idx & 15, n = idx >> 4;
        Bs[k][n] = b2f(((const u16*)Bv)[(long)bz * sB + (long)(n0 + n) * K + k0 + k]);
      }
    }
    __syncthreads();
    #pragma unroll
    for (int kk = 0; kk < TK; ++kk) {
      float av[4], bv[4];
      #pragma unroll
      for (int i = 0; i < 4; ++i) av[i] = As[kk][ty * 4 + i];
      #pragma unroll
      for (int j = 0; j < 4; ++j) bv[j] = Bs[kk][tx * 4 + j];
      #pragma unroll
      for (int i = 0; i < 4; ++i)
        #pragma unroll
        for (int j = 0; j < 4; ++j) acc[i][j] += av[i] * bv[j];
    }
    __syncthreads();
  }

  #pragma unroll
  for (int i = 0; i < 4; ++i) {
    int row = m0 + ty * 4 + i;
    if (row >= nc) continue;
    #pragma unroll
    for (int j = 0; j < 4; ++j) {
      int col = n0 + tx * 4 + j;
      float v = acc[i][j];
      if constexpr (MODE == 0) {
        ((u16*)Cv)[(long)bz * sC + (long)row * N + col] = f2b(v);
      } else if constexpr (MODE == 1) {
        if (col < nc)
          ((float*)Cv)[(long)bz * sC + (long)selb[row] * N_ + selb[col]] =
              floorf(v * 10000.0f) / 10000.0f;
      } else if constexpr (MODE == 2) {
        ((float*)Cv)[(long)bz * sC + (long)selb[row] * N + col] = v;
      } else {
        ((float*)Cv)[(long)bz * sC + (long)row * N + col] = dis2c[(long)bz * N_ + row] * v;
      }
    }
  }
}

// ---------------------------------------------------------------------------
// dis2c[j'] = rsqrt(1 + nnz over selected cols of cadj[sel[j']])
// ---------------------------------------------------------------------------
__global__ __launch_bounds__(256) void k_deg2c(
    const float* __restrict__ cadj, const int* __restrict__ sel,
    const int* __restrict__ ncArr, float* __restrict__ dis2c) {
  int b = blockIdx.x;
  int nc = ncArr[b];
  const int* sb = sel + (long)b * N_;
  for (int j = threadIdx.x; j < nc; j += 256) {
    const float* r = cadj + (long)b * NN_ + (long)sb[j] * N_;
    int cnt = 0;
    for (int j2 = 0; j2 < nc; ++j2) cnt += (r[sb[j2]] != 0.0f) ? 1 : 0;
    dis2c[(long)b * N_ + j] = rsqrtf(1.0f + (float)cnt);
  }
}

// ---------------------------------------------------------------------------
// fill x2 with tanh(b2) broadcast (value for all non-selected rows)
// ---------------------------------------------------------------------------
__global__ __launch_bounds__(256) void k_x2fill(
    const float* __restrict__ b2, float* __restrict__ x2) {
  long row = blockIdx.x;
  #pragma unroll
  for (int u = 0; u < F_ / 256; ++u) {
    int c = threadIdx.x + u * 256;
    x2[row * F_ + c] = tanhf(b2[c]);
  }
}

// ---------------------------------------------------------------------------
// selected x2 rows: tanh(dis_i*(sum_{j' bin} P2c_j' + P2c_i') + b2)
// ---------------------------------------------------------------------------
__global__ __launch_bounds__(256) void k_x2sel(
    const float* __restrict__ cadj, const float* __restrict__ P2c,
    const int* __restrict__ sel, const int* __restrict__ ncArr,
    const float* __restrict__ dis2c, const float* __restrict__ b2,
    float* __restrict__ x2) {
  int b = blockIdx.y, ip = blockIdx.x;
  int nc = ncArr[b];
  if (ip >= nc) return;
  const int* sb = sel + (long)b * N_;
  int row = sb[ip];
  __shared__ unsigned char flg[N_];
  const float* crow = cadj + (long)b * NN_ + (long)row * N_;
  for (int j = threadIdx.x; j < nc; j += 256)
    flg[j] = (crow[sb[j]] != 0.0f) ? 1 : 0;
  __syncthreads();
  float di = dis2c[(long)b * N_ + ip];
  for (int c = threadIdx.x; c < F_; c += 256) {
    float acc = P2c[((long)b * N_ + ip) * F_ + c];  // self (delta) term
    for (int j = 0; j < nc; ++j)
      if (flg[j]) acc += P2c[((long)b * N_ + j) * F_ + c];
    x2[((long)b * N_ + row) * F_ + c] = tanhf(di * acc + b2[c]);
  }
}

// ---------------------------------------------------------------------------
template<int W>
__global__ __launch_bounds__(256) void k_rowmean(
    const float* __restrict__ X, float* __restrict__ out) {
  long row = blockIdx.x;
  float s = 0.f;
  for (int j = threadIdx.x; j < W; j += 256) s += X[row * W + j];
  float r = blockReduceSum256(s);
  if (threadIdx.x == 0) out[row] = r / (float)W;
}

// ---------------------------------------------------------------------------
extern "C" void kernel_launch(void* const* d_in, const int* in_sizes, int n_in,
                              void* d_out, int out_size, void* d_ws, size_t ws_size,
                              hipStream_t stream) {
  const float* x     = (const float*)d_in[0];
  const float* adj   = (const float*)d_in[1];
  const int*   nsent = (const int*)d_in[2];
  const float* W1    = (const float*)d_in[3];
  const float* b1    = (const float*)d_in[4];
  const float* Watt  = (const float*)d_in[5];
  const float* batt  = (const float*)d_in[6];
  const float* W2    = (const float*)d_in[7];
  const float* b2    = (const float*)d_in[8];
  const int*   nout  = (const int*)d_in[9];

  const long NN = NN_;
  const long NH = (long)N_ * H_;
  const long NF = (long)N_ * F_;
  const int BN = B_ * N_;

  // output layout (flat concat, f32)
  float* out_x2   = (float*)d_out;
  float* out_cx   = out_x2 + (long)B_ * NF;
  float* out_cadj = out_cx + (long)B_ * NH;
  float* out_S    = out_cadj + (long)B_ * NN;
  float* out_im   = out_S + (long)B_ * NN;
  float* out_xs0  = out_im + BN;
  float* out_xs1  = out_xs0 + BN;

  // workspace (~127MB): P1 8.4 | x1 8.4 | smalls | W1T3 0.6 | Sc 33.6 |
  // pool 75.5 (xh/xm/xl -> StAc -> P2c)
  char* wsb = (char*)d_ws;
  float* P1      = (float*)wsb;
  float* x1      = P1 + (long)BN * H_;
  float* t       = x1 + (long)BN * H_;
  float* alpha   = t + BN;
  float* dis_bin = alpha + BN;
  float* dr      = dis_bin + BN;
  float* dc      = dr + BN;
  float* ca      = dc + BN;
  float* dis2c   = ca + BN;
  int*   sel     = (int*)(dis2c + BN);
  int*   rank    = sel + BN;
  int*   ncArr   = rank + BN;
  char*  p       = (char*)(ncArr + 64);
  p = (char*)(((size_t)p + 255) & ~(size_t)255);
  u16* W1h = (u16*)p;  p += (long)H_ * F_ * 2;
  u16* W1m = (u16*)p;  p += (long)H_ * F_ * 2;
  u16* W1l = (u16*)p;  p += (long)H_ * F_ * 2;
  u16* Sc  = (u16*)p;  p += (long)B_ * NN * 2;
  char* pool = p;                                  // 3*B*NF*2 = 75.5MB
  u16* xh = (u16*)pool;
  u16* xm = xh + (long)B_ * NF;
  u16* xl = xm + (long)B_ * NF;
  u16* StAc  = (u16*)pool;                         // alias (after G1)
  float* P2c = (float*)pool;                       // alias (after G7c)

  // K1: degrees
  k_degrees<<<dim3(BN), dim3(256), 0, stream>>>(adj, dis_bin, dr, dc);

  // split x and W1 into 3 bf16 planes
  k_split3<<<dim3(2048), dim3(256), 0, stream>>>(x, xh, xm, xl, (long)B_ * NF / 4);
  k_convT3<<<dim3(H_ / 32, F_ / 32, 1), dim3(256), 0, stream>>>(W1, W1h, W1m, W1l);

  // G1: P1 = dis_bin .* (x @ W1)  (split-3 MFMA, ~f32 accuracy)
  mgemm64s3<<<dim3(H_ / 64, BN / 64, 1), dim3(256), 0, stream>>>(
      xh, xm, xl, W1h, W1m, W1l, P1, H_, F_, dis_bin);

  // G2: x1 = relu(dis_i*(Bin(adj)@P1 + P1_i) + b1)  (sparse f32 exact)
  k_spmm_relu<<<dim3(BN), dim3(256), 0, stream>>>(adj, P1, dis_bin, b1, x1);

  // attention + sort + select + S
  k_att_dot<<<dim3(BN), dim3(256), 0, stream>>>(x1, Watt, t);
  k_alpha<<<dim3(BN), dim3(256), 0, stream>>>(adj, dis_bin, t, batt, alpha);
  k_cutmask<<<dim3(B_), dim3(1024), 0, stream>>>(alpha, nsent, nout, out_im, ca);
  k_select<<<dim3(B_), dim3(1024), 0, stream>>>(ca, sel, rank, ncArr);
  k_build_S<<<dim3(BN), dim3(256), 0, stream>>>(adj, dr, dc, ca, rank, out_S, Sc);

  // zero dense outputs that get compact scatters
  hipMemsetAsync(out_cx, 0, (size_t)B_ * NH * 4, stream);
  hipMemsetAsync(out_cadj, 0, (size_t)B_ * NN * 4, stream);

  // G6c: StAc[j'][k] = sum_i Sc[j'][i] * adj[i][k]   (bf16 A, f32 B)
  cgemm<0, 0, 0, 0><<<dim3(N_ / 64, N_ / 64, B_), dim3(256), 0, stream>>>(
      Sc, adj, StAc, N_, N_, NN, NN, NN, ncArr, sel, nullptr);

  // G7c: cadj[sel[j1]][sel[j2]] = floorq(StAc[j1] . Sc[j2])
  cgemm<0, 0, 1, 1><<<dim3(N_ / 64, N_ / 64, B_), dim3(256), 0, stream>>>(
      StAc, Sc, out_cadj, N_, N_, NN, NN, NN, ncArr, sel, nullptr);

  // dis2c
  k_deg2c<<<dim3(B_), dim3(256), 0, stream>>>(out_cadj, sel, ncArr, dis2c);

  // G5c: out_cx[sel[j']] = Sc[j'] @ x1
  cgemm<0, 0, 0, 2><<<dim3(H_ / 64, N_ / 64, B_), dim3(256), 0, stream>>>(
      Sc, x1, out_cx, H_, N_, NN, NH, NH, ncArr, sel, nullptr);

  // G8c: P2c[j'] = dis2c[j'] * (out_cx[sel[j']] @ W2)
  cgemm<1, 1, 0, 3><<<dim3(F_ / 64, N_ / 64, B_), dim3(256), 0, stream>>>(
      out_cx, W2, P2c, F_, H_, NH, 0, NF, ncArr, sel, dis2c);

  // x2: broadcast tanh(b2), then selected rows
  k_x2fill<<<dim3(BN), dim3(256), 0, stream>>>(b2, out_x2);
  k_x2sel<<<dim3(N_, B_), dim3(256), 0, stream>>>(
      out_cadj, P2c, sel, ncArr, dis2c, b2, out_x2);

  // means
  k_rowmean<H_><<<dim3(BN), dim3(256), 0, stream>>>(out_cx, out_xs0);
  k_rowmean<F_><<<dim3(BN), dim3(256), 0, stream>>>(out_x2, out_xs1);
}

// Round 6
// 544.210 us; speedup vs baseline: 1.6287x; 1.6287x over previous
//
#include <hip/hip_runtime.h>

#define B_ 16
#define N_ 1024
#define F_ 768
#define H_ 128

typedef float f32x4 __attribute__((ext_vector_type(4)));
typedef short s16x8 __attribute__((ext_vector_type(8)));
typedef unsigned short u16;
typedef u16 u16x8 __attribute__((ext_vector_type(8)));
typedef u16 u16x4 __attribute__((ext_vector_type(4)));

__device__ __forceinline__ u16 f2b(float f) {
  unsigned u = __float_as_uint(f);
  unsigned r = (u + 0x7FFFu + ((u >> 16) & 1u)) >> 16;
  return (u16)r;
}
__device__ __forceinline__ float b2f(u16 u) {
  return __uint_as_float(((unsigned)u) << 16);
}

__device__ __forceinline__ void gload16(const u16* g, u16* l) {
  __builtin_amdgcn_global_load_lds(
      (const __attribute__((address_space(1))) unsigned int*)g,
      (__attribute__((address_space(3))) unsigned int*)l, 16, 0, 0);
}

// ---------------------------------------------------------------------------
__device__ __forceinline__ float blockReduceSum256(float v) {
  __shared__ float red[4];
  #pragma unroll
  for (int o = 32; o > 0; o >>= 1) v += __shfl_down(v, o, 64);
  if ((threadIdx.x & 63) == 0) red[threadIdx.x >> 6] = v;
  __syncthreads();
  float r = red[0] + red[1] + red[2] + red[3];
  __syncthreads();
  return r;
}

// ---------------------------------------------------------------------------
// K1: dis_bin = rsqrt(1+nnz), dc = rsqrt(1+rowsum), dr = mask*dc
// ---------------------------------------------------------------------------
__global__ __launch_bounds__(256) void k_degrees(
    const float* __restrict__ adj, float* __restrict__ dis_bin,
    float* __restrict__ dr, float* __restrict__ dc) {
  long row = blockIdx.x;
  const float* a = adj + row * N_;
  float cnt = 0.f, sw = 0.f;
  for (int j = threadIdx.x; j < N_; j += 256) {
    float v = a[j];
    if (v != 0.0f) { cnt += 1.0f; sw += v; }
  }
  __shared__ float r1[4], r2[4];
  #pragma unroll
  for (int o = 32; o > 0; o >>= 1) { cnt += __shfl_down(cnt, o, 64); sw += __shfl_down(sw, o, 64); }
  if ((threadIdx.x & 63) == 0) { r1[threadIdx.x >> 6] = cnt; r2[threadIdx.x >> 6] = sw; }
  __syncthreads();
  if (threadIdx.x == 0) {
    float c = r1[0] + r1[1] + r1[2] + r1[3];
    float s = r2[0] + r2[1] + r2[2] + r2[3];
    dis_bin[row] = rsqrtf(c + 1.0f);
    float d = rsqrtf(s + 1.0f);
    dc[row] = d;
    dr[row] = (s > 0.0f) ? d : 0.0f;
  }
}

// ---------------------------------------------------------------------------
// split f32 -> 3 bf16 planes (h+m+l ~ f32 accuracy)
// ---------------------------------------------------------------------------
__global__ __launch_bounds__(256) void k_split3(
    const float* __restrict__ X, u16* __restrict__ Yh, u16* __restrict__ Ym,
    u16* __restrict__ Yl, long n4) {
  long i = (long)blockIdx.x * 256 + threadIdx.x;
  long stride = (long)gridDim.x * 256;
  for (; i < n4; i += stride) {
    f32x4 v = *(const f32x4*)(X + i * 4);
    u16x4 oh, om, ol;
    #pragma unroll
    for (int e = 0; e < 4; ++e) {
      float f = v[e];
      u16 h = f2b(f); float r1 = f - b2f(h);
      u16 m = f2b(r1); float r2 = r1 - b2f(m);
      u16 l = f2b(r2);
      oh[e] = h; om[e] = m; ol[e] = l;
    }
    *(u16x4*)(Yh + i * 4) = oh;
    *(u16x4*)(Ym + i * 4) = om;
    *(u16x4*)(Yl + i * 4) = ol;
  }
}

// transpose W1 [F][H] -> [H][F] with 3-way split
__global__ __launch_bounds__(256) void k_convT3(
    const float* __restrict__ X, u16* __restrict__ Yh, u16* __restrict__ Ym,
    u16* __restrict__ Yl) {
  __shared__ float tile[32][33];
  int tx = threadIdx.x & 31, ty = threadIdx.x >> 5;
  int r0 = blockIdx.y * 32, c0 = blockIdx.x * 32;
  #pragma unroll
  for (int i = 0; i < 4; ++i)
    tile[ty + i * 8][tx] = X[(long)(r0 + ty + i * 8) * H_ + (c0 + tx)];
  __syncthreads();
  #pragma unroll
  for (int i = 0; i < 4; ++i) {
    float v = tile[tx][ty + i * 8];
    long o = (long)(c0 + ty + i * 8) * F_ + (r0 + tx);
    u16 h = f2b(v); float r1 = v - b2f(h);
    u16 m = f2b(r1); float r2 = r1 - b2f(m);
    u16 l = f2b(r2);
    Yh[o] = h; Ym[o] = m; Yl[o] = l;
  }
}

// ---------------------------------------------------------------------------
// G1: P1 = scale .* ((A0+A1+A2) @ (B0+B1+B2)^T), 6-product split-3 MFMA.
// ---------------------------------------------------------------------------
__global__ __launch_bounds__(256) void mgemm64s3(
    const u16* __restrict__ A0, const u16* __restrict__ A1, const u16* __restrict__ A2,
    const u16* __restrict__ B0, const u16* __restrict__ B1, const u16* __restrict__ B2,
    float* __restrict__ C, int N, int K, const float* __restrict__ scale) {
  int m0 = blockIdx.y * 64, n0 = blockIdx.x * 64;
  __shared__ __align__(16) u16 As[3][64 * 72];
  __shared__ __align__(16) u16 Bs[3][64 * 72];
  const u16* Ap[3] = {A0 + (long)m0 * K, A1 + (long)m0 * K, A2 + (long)m0 * K};
  const u16* Bp[3] = {B0 + (long)n0 * K, B1 + (long)n0 * K, B2 + (long)n0 * K};
  int tid = threadIdx.x, lane = tid & 63, wave = tid >> 6;
  int wr = wave >> 1, wc = wave & 1, kg = lane >> 4, r16 = lane & 15;
  f32x4 acc[2][2] = {};

  for (int k0 = 0; k0 < K; k0 += 64) {
    #pragma unroll
    for (int t = 0; t < 3; ++t) {
      #pragma unroll
      for (int i = 0; i < 2; ++i) {
        int u = tid + i * 256;
        int row = u >> 3, seg = u & 7;
        *(u16x8*)(&As[t][row * 72 + seg * 8]) = *(const u16x8*)(Ap[t] + (long)row * K + k0 + seg * 8);
        *(u16x8*)(&Bs[t][row * 72 + seg * 8]) = *(const u16x8*)(Bp[t] + (long)row * K + k0 + seg * 8);
      }
    }
    __syncthreads();
    #pragma unroll
    for (int kk = 0; kk < 2; ++kk) {
      s16x8 ah[2], am[2], al[2], bh[2], bm[2], bl[2];
      #pragma unroll
      for (int m = 0; m < 2; ++m) {
        int off = (wr * 32 + m * 16 + r16) * 72 + kk * 32 + kg * 8;
        ah[m] = *(const s16x8*)(&As[0][off]);
        am[m] = *(const s16x8*)(&As[1][off]);
        al[m] = *(const s16x8*)(&As[2][off]);
      }
      #pragma unroll
      for (int n = 0; n < 2; ++n) {
        int off = (wc * 32 + n * 16 + r16) * 72 + kk * 32 + kg * 8;
        bh[n] = *(const s16x8*)(&Bs[0][off]);
        bm[n] = *(const s16x8*)(&Bs[1][off]);
        bl[n] = *(const s16x8*)(&Bs[2][off]);
      }
      #pragma unroll
      for (int m = 0; m < 2; ++m)
        #pragma unroll
        for (int n = 0; n < 2; ++n) {
          acc[m][n] = __builtin_amdgcn_mfma_f32_16x16x32_bf16(ah[m], bh[n], acc[m][n], 0, 0, 0);
          acc[m][n] = __builtin_amdgcn_mfma_f32_16x16x32_bf16(ah[m], bm[n], acc[m][n], 0, 0, 0);
          acc[m][n] = __builtin_amdgcn_mfma_f32_16x16x32_bf16(am[m], bh[n], acc[m][n], 0, 0, 0);
          acc[m][n] = __builtin_amdgcn_mfma_f32_16x16x32_bf16(am[m], bm[n], acc[m][n], 0, 0, 0);
          acc[m][n] = __builtin_amdgcn_mfma_f32_16x16x32_bf16(ah[m], bl[n], acc[m][n], 0, 0, 0);
          acc[m][n] = __builtin_amdgcn_mfma_f32_16x16x32_bf16(al[m], bh[n], acc[m][n], 0, 0, 0);
        }
    }
    __syncthreads();
  }

  #pragma unroll
  for (int m = 0; m < 2; ++m)
    #pragma unroll
    for (int r = 0; r < 4; ++r) {
      int row = m0 + wr * 32 + m * 16 + kg * 4 + r;
      float sc = scale[row];
      #pragma unroll
      for (int n = 0; n < 2; ++n) {
        int col = n0 + wc * 32 + n * 16 + r16;
        C[(long)row * N + col] = sc * acc[m][n][r];
      }
    }
}

// ---------------------------------------------------------------------------
// K2 (sparse, f32-exact): x1 = relu(dis_i*(sum_{adj_ij!=0} P1_j + P1_i) + b1)
// ---------------------------------------------------------------------------
__global__ __launch_bounds__(256) void k_spmm_relu(
    const float* __restrict__ adj, const float* __restrict__ P1,
    const float* __restrict__ dis_bin, const float* __restrict__ b1,
    float* __restrict__ x1) {
  long row = blockIdx.x;
  int b = (int)(row >> 10), i = (int)(row & 1023);
  const float* a = adj + row * N_;
  const float* Pb = P1 + (long)b * (long)N_ * H_;
  __shared__ int idxs[N_];
  __shared__ int tcnt[256];
  __shared__ float accs[H_];
  int tid = threadIdx.x;
  int base = tid * 4;
  f32x4 av = *(const f32x4*)(a + base);
  int c0 = (av[0] != 0.0f) + (av[1] != 0.0f) + (av[2] != 0.0f) + (av[3] != 0.0f);
  tcnt[tid] = c0;
  __syncthreads();
  for (int off = 1; off < 256; off <<= 1) {
    int add = (tid >= off) ? tcnt[tid - off] : 0;
    __syncthreads();
    tcnt[tid] += add;
    __syncthreads();
  }
  int pos = tcnt[tid] - c0;
  int n = tcnt[255];
  if (av[0] != 0.0f) idxs[pos++] = base;
  if (av[1] != 0.0f) idxs[pos++] = base + 1;
  if (av[2] != 0.0f) idxs[pos++] = base + 2;
  if (av[3] != 0.0f) idxs[pos++] = base + 3;
  __syncthreads();
  int c = tid & 127, team = tid >> 7;
  float acc = 0.f;
  for (int u = team; u < n; u += 2)
    acc += Pb[(long)idxs[u] * H_ + c];
  if (team == 1) accs[c] = acc;
  __syncthreads();
  if (team == 0) {
    float tot = acc + accs[c] + Pb[(long)i * H_ + c];
    float v = dis_bin[row] * tot + b1[c];
    x1[row * H_ + c] = fmaxf(v, 0.0f);
  }
}

// ---------------------------------------------------------------------------
// Big MFMA GEMM: 128x128 tile, BK=32, global_load_lds staging.
// C = A[M][K] @ Bt[N][K]^T.
// MODE 0: f32 C=acc | 1: bf16 C | 2: f32 floorq + rowcnt atomics |
// 3: f32 tanh(sc*(acc+Add)+bias) | 4: f32 scale[row]*acc
// ---------------------------------------------------------------------------
template<int MODE>
__global__ __launch_bounds__(256) void mgemm(
    const u16* __restrict__ A, const u16* __restrict__ Bt, void* __restrict__ Cv,
    int M, int N, int K, long sA, long sB, long sC,
    const float* __restrict__ scale, const float* __restrict__ Add, long sAdd,
    const float* __restrict__ bias, int* __restrict__ rowcnt) {
  int bz = blockIdx.z;
  int m0 = blockIdx.y * 128, n0 = blockIdx.x * 128;
  const u16* Ab = A + (long)bz * sA + (long)m0 * K;
  const u16* Bb = Bt + (long)bz * sB + (long)n0 * K;
  __shared__ __align__(16) u16 As[128 * 32];
  __shared__ __align__(16) u16 Bs[128 * 32];
  int tid = threadIdx.x;
  int lane = tid & 63, wave = tid >> 6;
  int wr = wave >> 1, wc = wave & 1;
  int kg = lane >> 4, r16 = lane & 15;
  const u16* ga = Ab + (long)(tid >> 2) * K + (tid & 3) * 8;
  const u16* gb = Bb + (long)(tid >> 2) * K + (tid & 3) * 8;
  f32x4 acc[4][4] = {};

  for (int k0 = 0; k0 < K; k0 += 32) {
    gload16(ga + k0, &As[tid * 8]);
    gload16(ga + (long)64 * K + k0, &As[2048 + tid * 8]);
    gload16(gb + k0, &Bs[tid * 8]);
    gload16(gb + (long)64 * K + k0, &Bs[2048 + tid * 8]);
    __syncthreads();
    s16x8 af[4], bfr[4];
    #pragma unroll
    for (int m = 0; m < 4; ++m)
      af[m] = *(const s16x8*)(&As[(wr * 64 + m * 16 + r16) * 32 + kg * 8]);
    #pragma unroll
    for (int n = 0; n < 4; ++n)
      bfr[n] = *(const s16x8*)(&Bs[(wc * 64 + n * 16 + r16) * 32 + kg * 8]);
    #pragma unroll
    for (int m = 0; m < 4; ++m)
      #pragma unroll
      for (int n = 0; n < 4; ++n)
        acc[m][n] = __builtin_amdgcn_mfma_f32_16x16x32_bf16(af[m], bfr[n], acc[m][n], 0, 0, 0);
    __syncthreads();
  }

  if constexpr (MODE == 2) {
    int* cnt = (int*)As;
    if (tid < 128) cnt[tid] = 0;
    __syncthreads();
    #pragma unroll
    for (int m = 0; m < 4; ++m) {
      #pragma unroll
      for (int r = 0; r < 4; ++r) {
        int lrow = wr * 64 + m * 16 + kg * 4 + r;
        int row = m0 + lrow;
        int nz = 0;
        #pragma unroll
        for (int n = 0; n < 4; ++n) {
          int col = n0 + wc * 64 + n * 16 + r16;
          float q = floorf(acc[m][n][r] * 10000.0f) / 10000.0f;
          ((float*)Cv)[(long)bz * sC + (long)row * N + col] = q;
          nz += (q != 0.0f) ? 1 : 0;
        }
        atomicAdd(&cnt[lrow], nz);
      }
    }
    __syncthreads();
    if (tid < 128) atomicAdd(&rowcnt[(long)bz * N_ + m0 + tid], cnt[tid]);
    return;
  }

  #pragma unroll
  for (int m = 0; m < 4; ++m) {
    #pragma unroll
    for (int r = 0; r < 4; ++r) {
      int row = m0 + wr * 64 + m * 16 + kg * 4 + r;
      float sc = 0.f;
      if constexpr (MODE == 3) sc = scale[(long)bz * N_ + row];
      if constexpr (MODE == 4) sc = scale[row];
      #pragma unroll
      for (int n = 0; n < 4; ++n) {
        int col = n0 + wc * 64 + n * 16 + r16;
        float v = acc[m][n][r];
        long cidx = (long)bz * sC + (long)row * N + col;
        if constexpr (MODE == 0) {
          ((float*)Cv)[cidx] = v;
        } else if constexpr (MODE == 1) {
          ((u16*)Cv)[cidx] = f2b(v);
        } else if constexpr (MODE == 3) {
          v = sc * (v + Add[(long)bz * sAdd + (long)row * N + col]) + bias[col];
          ((float*)Cv)[cidx] = tanhf(v);
        } else if constexpr (MODE == 4) {
          ((float*)Cv)[cidx] = sc * v;
        }
      }
    }
  }
}

// ---------------------------------------------------------------------------
// Small-N MFMA GEMM: 64x64 tile, BK=64, reg-staged, pad-72 LDS. MODE 0 only.
// ---------------------------------------------------------------------------
__global__ __launch_bounds__(256) void mgemm64(
    const u16* __restrict__ A, const u16* __restrict__ Bt, float* __restrict__ C,
    int N, int K, long sA, long sB, long sC) {
  int bz = blockIdx.z;
  int m0 = blockIdx.y * 64, n0 = blockIdx.x * 64;
  const u16* Ab = A + (long)bz * sA + (long)m0 * K;
  const u16* Bb = Bt + (long)bz * sB + (long)n0 * K;
  __shared__ __align__(16) u16 As[64 * 72];
  __shared__ __align__(16) u16 Bs[64 * 72];
  int tid = threadIdx.x;
  int lane = tid & 63, wave = tid >> 6;
  int wr = wave >> 1, wc = wave & 1;
  int kg = lane >> 4, r16 = lane & 15;
  f32x4 acc[2][2] = {};

  for (int k0 = 0; k0 < K; k0 += 64) {
    #pragma unroll
    for (int i = 0; i < 2; ++i) {
      int u = tid + i * 256;
      int row = u >> 3, seg = u & 7;
      *(u16x8*)(&As[row * 72 + seg * 8]) = *(const u16x8*)(Ab + (long)row * K + k0 + seg * 8);
      *(u16x8*)(&Bs[row * 72 + seg * 8]) = *(const u16x8*)(Bb + (long)row * K + k0 + seg * 8);
    }
    __syncthreads();
    #pragma unroll
    for (int kk = 0; kk < 2; ++kk) {
      s16x8 af[2], bfr[2];
      #pragma unroll
      for (int m = 0; m < 2; ++m)
        af[m] = *(const s16x8*)(&As[(wr * 32 + m * 16 + r16) * 72 + kk * 32 + kg * 8]);
      #pragma unroll
      for (int n = 0; n < 2; ++n)
        bfr[n] = *(const s16x8*)(&Bs[(wc * 32 + n * 16 + r16) * 72 + kk * 32 + kg * 8]);
      #pragma unroll
      for (int m = 0; m < 2; ++m)
        #pragma unroll
        for (int n = 0; n < 2; ++n)
          acc[m][n] = __builtin_amdgcn_mfma_f32_16x16x32_bf16(af[m], bfr[n], acc[m][n], 0, 0, 0);
    }
    __syncthreads();
  }

  #pragma unroll
  for (int m = 0; m < 2; ++m)
    #pragma unroll
    for (int r = 0; r < 4; ++r) {
      int row = m0 + wr * 32 + m * 16 + kg * 4 + r;
      #pragma unroll
      for (int n = 0; n < 2; ++n) {
        int col = n0 + wc * 32 + n * 16 + r16;
        C[(long)bz * sC + (long)row * N + col] = acc[m][n][r];
      }
    }
}

// ---------------------------------------------------------------------------
// transpose-convert: X[b][R][C] f32 -> Y[b][C][R] bf16
// ---------------------------------------------------------------------------
__global__ __launch_bounds__(256) void k_convT(
    const float* __restrict__ X, u16* __restrict__ Y, int R, int C,
    long sX, long sY) {
  __shared__ float tile[32][33];
  const float* Xb = X + (long)blockIdx.z * sX;
  u16* Yb = Y + (long)blockIdx.z * sY;
  int tx = threadIdx.x & 31, ty = threadIdx.x >> 5;
  int r0 = blockIdx.y * 32, c0 = blockIdx.x * 32;
  #pragma unroll
  for (int i = 0; i < 4; ++i)
    tile[ty + i * 8][tx] = Xb[(long)(r0 + ty + i * 8) * C + (c0 + tx)];
  __syncthreads();
  #pragma unroll
  for (int i = 0; i < 4; ++i)
    Yb[(long)(c0 + ty + i * 8) * R + (r0 + tx)] = f2b(tile[tx][ty + i * 8]);
}

// flat convert f32 -> bf16
__global__ __launch_bounds__(256) void k_conv(
    const float* __restrict__ X, u16* __restrict__ Y, long n4) {
  long i = (long)blockIdx.x * 256 + threadIdx.x;
  long stride = (long)gridDim.x * 256;
  for (; i < n4; i += stride) {
    f32x4 v = *(const f32x4*)(X + i * 4);
    u16x4 o;
    o[0] = f2b(v[0]); o[1] = f2b(v[1]); o[2] = f2b(v[2]); o[3] = f2b(v[3]);
    *(u16x4*)(Y + i * 4) = o;
  }
}

// binarize: Y[i] = X[i] != 0 ? bf16(1.0) : 0
__global__ __launch_bounds__(256) void k_convbin(
    const float* __restrict__ X, u16* __restrict__ Y, long n) {
  long i = (long)blockIdx.x * 256 + threadIdx.x;
  long stride = (long)gridDim.x * 256;
  for (; i < n; i += stride)
    Y[i] = (X[i] != 0.0f) ? (u16)0x3F80 : (u16)0;
}

// cnt -> dis2
__global__ __launch_bounds__(256) void k_cnt2dis(
    const int* __restrict__ cnt, float* __restrict__ dis2, int n) {
  int i = blockIdx.x * 256 + threadIdx.x;
  if (i < n) dis2[i] = rsqrtf(1.0f + (float)cnt[i]);
}

// ---------------------------------------------------------------------------
// K4: t[row] = dot(x1[row,:], Watt)
// ---------------------------------------------------------------------------
__global__ __launch_bounds__(256) void k_att_dot(
    const float* __restrict__ x1, const float* __restrict__ Watt,
    float* __restrict__ t) {
  long row = blockIdx.x;
  float v = 0.f;
  if (threadIdx.x < H_) v = x1[row * H_ + threadIdx.x] * Watt[threadIdx.x];
  float s = blockReduceSum256(v);
  if (threadIdx.x == 0) t[row] = s;
}

// ---------------------------------------------------------------------------
// K5: alpha
// ---------------------------------------------------------------------------
__global__ __launch_bounds__(256) void k_alpha(
    const float* __restrict__ adj, const float* __restrict__ dis_bin,
    const float* __restrict__ t, const float* __restrict__ batt,
    float* __restrict__ alpha) {
  long row = blockIdx.x;
  int b = (int)(row >> 10), i = (int)(row & 1023);
  const float* a = adj + row * N_;
  const float* db = dis_bin + (long)b * N_;
  const float* tb = t + (long)b * N_;
  float s = 0.f;
  for (int j = threadIdx.x; j < N_; j += 256)
    if (a[j] != 0.0f) s += db[j] * tb[j];
  s = blockReduceSum256(s);
  if (threadIdx.x == 0) {
    float di = db[i];
    float pre = di * (s + di * tb[i]) + batt[0];
    float z = pre * pre;
    alpha[row] = 1.0f / (1.0f + expf(-z));
  }
}

// ---------------------------------------------------------------------------
// K6: per-batch stable descending sort, cut, index_mask, cut_alpha
// ---------------------------------------------------------------------------
__global__ __launch_bounds__(1024) void k_cutmask(
    const float* __restrict__ alpha, const int* __restrict__ num_sent,
    const int* __restrict__ nout, float* __restrict__ index_mask,
    float* __restrict__ ca) {
  int b = blockIdx.x, tid = threadIdx.x;
  __shared__ unsigned long long keys[N_];
  __shared__ int cs[N_];
  __shared__ int pos_s;
  float av = alpha[(long)b * N_ + tid];
  unsigned int bits = __float_as_uint(av);
  keys[tid] = ((unsigned long long)(0xFFFFFFFFu - bits) << 32) | (unsigned int)tid;
  __syncthreads();
  for (int kk = 2; kk <= N_; kk <<= 1) {
    for (int j = kk >> 1; j > 0; j >>= 1) {
      int ixj = tid ^ j;
      if (ixj > tid) {
        unsigned long long x = keys[tid], y = keys[ixj];
        bool up = ((tid & kk) == 0);
        if ((x > y) == up) { keys[tid] = y; keys[ixj] = x; }
      }
      __syncthreads();
    }
  }
  int ns = num_sent[b];
  int idx = (int)(keys[tid] & 0xFFFFFFFFull);
  cs[tid] = (idx < ns) ? 1 : 0;
  __syncthreads();
  for (int off = 1; off < N_; off <<= 1) {
    int add = (tid >= off) ? cs[tid - off] : 0;
    __syncthreads();
    cs[tid] += add;
    __syncthreads();
  }
  int k = nout[0];
  if (tid == 0) pos_s = 0;
  __syncthreads();
  if (cs[tid] >= k && (tid == 0 || cs[tid - 1] < k)) pos_s = tid;
  __syncthreads();
  float cut = __uint_as_float(0xFFFFFFFFu - (unsigned int)(keys[pos_s] >> 32));
  float myalpha = __uint_as_float(0xFFFFFFFFu - (unsigned int)(keys[tid] >> 32));
  index_mask[(long)b * N_ + idx] = (tid <= pos_s) ? 1.0f : 0.0f;
  ca[(long)b * N_ + idx] = fmaxf((myalpha + 1e-7f) - cut, 0.0f);
}

// ---------------------------------------------------------------------------
// K7: S build + L1 row-normalize
// ---------------------------------------------------------------------------
__global__ __launch_bounds__(256) void k_build_S(
    const float* __restrict__ adj, const float* __restrict__ dr,
    const float* __restrict__ dc, const float* __restrict__ ca,
    float* __restrict__ S) {
  long row = blockIdx.x;
  int b = (int)(row >> 10), i = (int)(row & 1023);
  const float* a = adj + row * N_;
  const float* dcb = dc + (long)b * N_;
  const float* cab = ca + (long)b * N_;
  float dri = dr[row];
  __shared__ float pre[N_];
  float ls = 0.f;
  for (int j = threadIdx.x; j < N_; j += 256) {
    float avv = a[j] + ((j == i) ? 1.0f : 0.0f);
    float v = dri * avv * dcb[j] * cab[j];
    pre[j] = v;
    ls += v;
  }
  float sum = blockReduceSum256(ls);
  float denom = fmaxf(sum, 1e-12f);
  for (int j = threadIdx.x; j < N_; j += 256)
    S[row * N_ + j] = pre[j] / denom;
}

// ---------------------------------------------------------------------------
template<int W>
__global__ __launch_bounds__(256) void k_rowmean(
    const float* __restrict__ X, float* __restrict__ out) {
  long row = blockIdx.x;
  float s = 0.f;
  for (int j = threadIdx.x; j < W; j += 256) s += X[row * W + j];
  float r = blockReduceSum256(s);
  if (threadIdx.x == 0) out[row] = r / (float)W;
}

// ---------------------------------------------------------------------------
extern "C" void kernel_launch(void* const* d_in, const int* in_sizes, int n_in,
                              void* d_out, int out_size, void* d_ws, size_t ws_size,
                              hipStream_t stream) {
  const float* x     = (const float*)d_in[0];
  const float* adj   = (const float*)d_in[1];
  const int*   nsent = (const int*)d_in[2];
  const float* W1    = (const float*)d_in[3];
  const float* b1    = (const float*)d_in[4];
  const float* Watt  = (const float*)d_in[5];
  const float* batt  = (const float*)d_in[6];
  const float* W2    = (const float*)d_in[7];
  const float* b2    = (const float*)d_in[8];
  const int*   nout  = (const int*)d_in[9];

  const long NN = (long)N_ * N_;
  const long NH = (long)N_ * H_;
  const long NF = (long)N_ * F_;
  const int BN = B_ * N_;

  // output layout (flat concat, f32)
  float* out_x2   = (float*)d_out;
  float* out_cx   = out_x2 + (long)B_ * NF;
  float* out_cadj = out_cx + (long)B_ * NH;
  float* out_S    = out_cadj + (long)B_ * NN;
  float* out_im   = out_S + (long)B_ * NN;
  float* out_xs0  = out_im + BN;
  float* out_xs1  = out_xs0 + BN;

  // workspace (~140MB, round-4-proven scale)
  char* wsb = (char*)d_ws;
  float* P1      = (float*)wsb;
  float* x1      = P1 + (long)B_ * NH;
  float* t       = x1 + (long)B_ * NH;
  float* alpha   = t + BN;
  float* dis_bin = alpha + BN;
  float* dr      = dis_bin + BN;
  float* dc      = dr + BN;
  float* ca      = dc + BN;
  float* dis2    = ca + BN;
  int*   rowcnt  = (int*)(dis2 + BN);
  char*  p       = (char*)(rowcnt + BN);
  p = (char*)(((size_t)p + 255) & ~(size_t)255);
  u16* W1h   = (u16*)p;  p += (long)H_ * F_ * 2;
  u16* W1m   = (u16*)p;  p += (long)H_ * F_ * 2;
  u16* W1l   = (u16*)p;  p += (long)H_ * F_ * 2;
  u16* W2T   = (u16*)p;  p += (long)H_ * F_ * 2;
  u16* PT    = (u16*)p;  p += (long)B_ * NH * 2;   // x1T
  u16* St    = (u16*)p;  p += (long)B_ * NN * 2;   // xh -> St -> cbin
  u16* adjT  = (u16*)p;  p += (long)B_ * NN * 2;   // xm -> adjT -> P2T
  float* P2f = (float*)p;                           // xl -> P2f (50MB)
  u16* xh    = St;
  u16* xm    = adjT;
  u16* xl    = (u16*)P2f;
  u16* cx_bf = (u16*)P1;
  u16* x1T   = PT;
  u16* cbin  = St;
  u16* P2T   = adjT;
  u16* StA   = (u16*)out_x2;   // scratch in unwritten output region

  // K1: degrees
  k_degrees<<<dim3(BN), dim3(256), 0, stream>>>(adj, dis_bin, dr, dc);

  // split x and W1 into 3 bf16 planes
  k_split3<<<dim3(2048), dim3(256), 0, stream>>>(x, xh, xm, xl, (long)B_ * NF / 4);
  k_convT3<<<dim3(H_ / 32, F_ / 32, 1), dim3(256), 0, stream>>>(W1, W1h, W1m, W1l);

  // zero rowcnt (used by G7 epilogue)
  hipMemsetAsync(rowcnt, 0, (size_t)BN * 4, stream);

  // G1: P1 = dis_bin .* (x @ W1)  (split-3 MFMA, ~f32 accuracy)
  mgemm64s3<<<dim3(H_ / 64, BN / 64, 1), dim3(256), 0, stream>>>(
      xh, xm, xl, W1h, W1m, W1l, P1, H_, F_, dis_bin);

  // G2: x1 = relu(dis_i*(Bin(adj)@P1 + P1_i) + b1)  (sparse f32 exact)
  k_spmm_relu<<<dim3(BN), dim3(256), 0, stream>>>(adj, P1, dis_bin, b1, x1);

  // attention + sort + S (f32)
  k_att_dot<<<dim3(BN), dim3(256), 0, stream>>>(x1, Watt, t);
  k_alpha<<<dim3(BN), dim3(256), 0, stream>>>(adj, dis_bin, t, batt, alpha);
  k_cutmask<<<dim3(B_), dim3(1024), 0, stream>>>(alpha, nsent, nout, out_im, ca);
  k_build_S<<<dim3(BN), dim3(256), 0, stream>>>(adj, dr, dc, ca, out_S);

  // St = S^T, x1T = x1^T, adjT = adj^T (bf16)
  k_convT<<<dim3(N_ / 32, N_ / 32, B_), dim3(256), 0, stream>>>(out_S, St, N_, N_, NN, NN);
  k_convT<<<dim3(H_ / 32, N_ / 32, B_), dim3(256), 0, stream>>>(x1, x1T, N_, H_, NH, NH);
  k_convT<<<dim3(N_ / 32, N_ / 32, B_), dim3(256), 0, stream>>>(adj, adjT, N_, N_, NN, NN);

  // G5: coarse_x = S^T @ x1  (bf16 MFMA)
  mgemm64<<<dim3(H_ / 64, N_ / 64, B_), dim3(256), 0, stream>>>(
      St, x1T, out_cx, H_, N_, NN, NH, NH);
  k_rowmean<H_><<<dim3(BN), dim3(256), 0, stream>>>(out_cx, out_xs0);

  // G6: StA = S^T @ adj (bf16 out)
  mgemm<1><<<dim3(N_ / 128, N_ / 128, B_), dim3(256), 0, stream>>>(
      St, adjT, StA, N_, N_, N_, NN, NN, NN, nullptr, nullptr, 0, nullptr, nullptr);

  // G7: coarse_adj = floorq(StA @ S) + fused row-nnz counts
  mgemm<2><<<dim3(N_ / 128, N_ / 128, B_), dim3(256), 0, stream>>>(
      StA, St, out_cadj, N_, N_, N_, NN, NN, NN, nullptr, nullptr, 0, nullptr, rowcnt);

  // dis2 from fused counts
  k_cnt2dis<<<dim3((BN + 255) / 256), dim3(256), 0, stream>>>(rowcnt, dis2, BN);

  // cx_bf, W2T
  k_conv<<<dim3(2048), dim3(256), 0, stream>>>(out_cx, cx_bf, (long)B_ * NH / 4);
  k_convT<<<dim3(F_ / 32, H_ / 32, 1), dim3(256), 0, stream>>>(W2, W2T, H_, F_, 0, 0);

  // G8: P2f = dis2 .* (coarse_x @ W2)  (big-tile MFMA, z=1)
  mgemm<4><<<dim3(F_ / 128, BN / 128, 1), dim3(256), 0, stream>>>(
      cx_bf, W2T, P2f, BN, F_, H_, 0, 0, 0, dis2, nullptr, 0, nullptr, nullptr);

  // P2T, cbin
  k_convT<<<dim3(F_ / 32, N_ / 32, B_), dim3(256), 0, stream>>>(P2f, P2T, N_, F_, NF, NF);
  k_convbin<<<dim3(2048), dim3(256), 0, stream>>>(out_cadj, cbin, (long)B_ * NN);

  // G9: x2 = tanh(dis2_i*(cbin@P2 + P2_i) + b2)   (overwrites StA scratch)
  mgemm<3><<<dim3(F_ / 128, N_ / 128, B_), dim3(256), 0, stream>>>(
      cbin, P2T, out_x2, N_, F_, N_, NN, NF, NF, dis2, P2f, NF, b2, nullptr);

  k_rowmean<F_><<<dim3(BN), dim3(256), 0, stream>>>(out_x2, out_xs1);
}